// Round 3
// baseline (209.650 us; speedup 1.0000x reference)
//
#include <hip/hip_runtime.h>
#include <hip/hip_bf16.h>

typedef unsigned short u16;
typedef __attribute__((ext_vector_type(8))) short bf16x8;
typedef __attribute__((ext_vector_type(4))) float f32x4;

#define AS1 __attribute__((address_space(1)))
#define AS3 __attribute__((address_space(3)))

// ---- constants for this problem ----
#define Bx 8
#define Tt 2048
#define Dd 1024
#define Nn 256
#define Mm (Bx*Tt)          // 16384
#define CHAINS (Bx*Nn)      // 2048
#define NCH 32
#define TC 64               // T / NCH
#define NCOMB 1792          // 768 (abc) + 1024 (d)

#define VMCNT4 asm volatile("s_waitcnt vmcnt(4)" ::: "memory")
#define VMCNT0 asm volatile("s_waitcnt vmcnt(0)" ::: "memory")
#define BARR   __builtin_amdgcn_s_barrier()
#define SCHEDB __builtin_amdgcn_sched_barrier(0)

__device__ __forceinline__ u16 f2bf(float f) {
  union { float f; unsigned u; } v; v.f = f;
  unsigned u = v.u;
  u += 0x7fffu + ((u >> 16) & 1u);   // RNE
  return (u16)(u >> 16);
}

__device__ __forceinline__ void gload_lds16(const void* g, void* l) {
  __builtin_amdgcn_global_load_lds((AS1 void*)(g), (AS3 void*)(l), 16, 0, 0);
}

// ---------------- x fp32 -> bf16 ----------------
__global__ void cvt_x_kernel(const float* __restrict__ x, u16* __restrict__ xb) {
  int i = blockIdx.x * blockDim.x + threadIdx.x;      // 4 floats per thread
  float4 v = ((const float4*)x)[i];
  unsigned lo = (unsigned)f2bf(v.x) | ((unsigned)f2bf(v.y) << 16);
  unsigned hi = (unsigned)f2bf(v.z) | ((unsigned)f2bf(v.w) << 16);
  ((uint2*)xb)[i] = make_uint2(lo, hi);
}

// ---------------- weight pack: transpose + convert ----------------
__global__ void pack_w_kernel(const float* __restrict__ Wa, const float* __restrict__ Wb,
                              const float* __restrict__ Wc, const float* __restrict__ Wd,
                              const float* __restrict__ Wy,
                              u16* __restrict__ Wcomb, u16* __restrict__ Wyt) {
  __shared__ float tile[32][33];
  int z = blockIdx.z;
  const float* src; u16* dst; int R, C, dld;
  if (z < 3)       { src = (z==0?Wa:(z==1?Wb:Wc)); dst = Wcomb + (size_t)z*256*1024; R=1024; C=256;  dld=1024; }
  else if (z == 3) { src = Wd; dst = Wcomb + (size_t)768*1024; R=1024; C=1024; dld=1024; }
  else             { src = Wy; dst = Wyt; R=256;  C=1024; dld=256;  }
  int c0 = blockIdx.x * 32, r0 = blockIdx.y * 32;
  if (c0 >= C || r0 >= R) return;
  int tx = threadIdx.x & 31, ty = threadIdx.x >> 5;   // 32x8
  #pragma unroll
  for (int i = 0; i < 32; i += 8)
    tile[ty + i][tx] = src[(size_t)(r0 + ty + i)*C + (c0 + tx)];
  __syncthreads();
  #pragma unroll
  for (int i = 0; i < 32; i += 8) {
    int c = c0 + ty + i, r = r0 + tx;
    dst[(size_t)c*dld + r] = f2bf(tile[tx][ty + i]);
  }
}

// ---------------- 256x256 8-phase GEMM: C[M,*] = A[M,K] * Bt[*,K]^T ----------------
// 8 waves (2 wm x 4 wn). Wave output: quadrant (mq,nq): rows mq*128+wm*64+mi*16,
// cols nq*128+wn*32+ni*16 (mi<4, ni<2). Phases p0=(0,0) p1=(0,1) p2=(1,0) p3=(1,1).
// Stage units = 64 rows (1 gload_lds/thread). Per-tile stage order (for tile t+1):
// p0:{A0,A1} p1:{B0,B1} p2:{B2,B3} p3:{A2,A3}; ledger -> vmcnt(4) at end of p0,p1,p3.
// LDS: A [2][256][64] u16 @0, B same @32768 (u16 idx). Slot-XOR swizzle slot^=(row&7),
// applied on global source (linear LDS dest) and on ds_read (G21).
template<int EPI>
__global__ __launch_bounds__(512, 2) void gemm8p_kernel(
    const u16* __restrict__ A, const u16* __restrict__ Bt, int K, int gx,
    float* __restrict__ outA, float* __restrict__ outO,
    const float* __restrict__ b0, const float* __restrict__ b1,
    const float* __restrict__ b2, const float* __restrict__ b3) {
  extern __shared__ u16 lds[];
  const int tid  = threadIdx.x;
  const int lane = tid & 63, wid = tid >> 6;
  const int wm = wid >> 2, wn = wid & 3;

  // XCD-aware bijective swizzle (nwg % 8 == 0 for both launches)
  const int nwg = gridDim.x;
  const int h   = blockIdx.x;
  const int id  = (h & 7) * (nwg >> 3) + (h >> 3);
  const int mt  = id / gx, nt = id % gx;
  const int m0  = mt * 256, n0 = nt * 256;
  const int NT  = K >> 6;

  // staging thread mapping
  const int rl  = tid >> 3;            // row within 64-row unit
  const int ssl = (tid & 7) ^ (rl & 7);// pre-swizzled source 16B slot

  // fragment-read lane mapping
  const int lr = lane & 15, kq = lane >> 4, sw = lane & 7;

  auto stA = [&](int q, int bn, int kn) {
    gload_lds16(A + (size_t)(m0 + q*64 + rl)*K + kn + ssl*8,
                lds + bn*16384 + q*4096 + wid*512);
  };
  auto stB = [&](int q, int bn, int kn) {
    gload_lds16(Bt + (size_t)(n0 + q*64 + rl)*K + kn + ssl*8,
                lds + 32768 + bn*16384 + q*4096 + wid*512);
  };
  auto rdA = [&](int buf, int row, int kk) -> bf16x8 {
    return *(const bf16x8*)(lds + buf*16384 + row*64 + (((kk*4 + kq) ^ sw) << 3));
  };
  auto rdB = [&](int buf, int row, int kk) -> bf16x8 {
    return *(const bf16x8*)(lds + 32768 + buf*16384 + row*64 + (((kk*4 + kq) ^ sw) << 3));
  };

  f32x4 acc[2][2][4][2] = {};

  auto mma8 = [&](f32x4 (&ac)[4][2], const bf16x8 (&af)[4][2], const bf16x8 (&bf)[2][2]) {
    __builtin_amdgcn_s_setprio(1);
    #pragma unroll
    for (int kk = 0; kk < 2; ++kk)
      #pragma unroll
      for (int mi = 0; mi < 4; ++mi)
        #pragma unroll
        for (int ni = 0; ni < 2; ++ni)
          ac[mi][ni] = __builtin_amdgcn_mfma_f32_16x16x32_bf16(af[mi][kk], bf[ni][kk], ac[mi][ni], 0, 0, 0);
    __builtin_amdgcn_s_setprio(0);
  };

  // ---- prologue: stage tile 0 in ledger order [A0,A1,B0,B1,B2,B3,A2,A3] ----
  stA(0,0,0); stA(1,0,0); stB(0,0,0); stB(1,0,0);
  stB(2,0,0); stB(3,0,0); stA(2,0,0); stA(3,0,0);
  VMCNT4;           // A0,A1,B0,B1 landed; {B2,B3,A2,A3} in flight
  BARR; SCHEDB;

  for (int t = 0; t < NT; ++t) {
    const int buf = t & 1, bn = buf ^ 1;
    const int kn = (t + 1 < NT) ? (t + 1) << 6 : 0;   // clamped fake stage past end
    bf16x8 a0f[4][2], a1f[4][2], b0f[2][2], b1f[2][2];

    // ---- phase 0: quadrant (0,0) ----
    #pragma unroll
    for (int mi = 0; mi < 4; ++mi) {
      a0f[mi][0] = rdA(buf, wm*64 + mi*16 + lr, 0);
      a0f[mi][1] = rdA(buf, wm*64 + mi*16 + lr, 1);
    }
    #pragma unroll
    for (int ni = 0; ni < 2; ++ni) {
      b0f[ni][0] = rdB(buf, wn*32 + ni*16 + lr, 0);
      b0f[ni][1] = rdB(buf, wn*32 + ni*16 + lr, 1);
    }
    stA(0, bn, kn); stA(1, bn, kn);
    VMCNT4;          // covers p1's B2,B3 (current tile)
    BARR;
    mma8(acc[0][0], a0f, b0f);
    BARR; SCHEDB;

    // ---- phase 1: quadrant (0,1) ----
    #pragma unroll
    for (int ni = 0; ni < 2; ++ni) {
      b1f[ni][0] = rdB(buf, 128 + wn*32 + ni*16 + lr, 0);
      b1f[ni][1] = rdB(buf, 128 + wn*32 + ni*16 + lr, 1);
    }
    stB(0, bn, kn); stB(1, bn, kn);
    VMCNT4;          // covers p2's A2,A3 (current tile)
    BARR;
    mma8(acc[0][1], a0f, b1f);
    BARR; SCHEDB;

    // ---- phase 2: quadrant (1,0) ----
    #pragma unroll
    for (int mi = 0; mi < 4; ++mi) {
      a1f[mi][0] = rdA(buf, 128 + wm*64 + mi*16 + lr, 0);
      a1f[mi][1] = rdA(buf, 128 + wm*64 + mi*16 + lr, 1);
    }
    stB(2, bn, kn); stB(3, bn, kn);
    BARR;            // p3 needs no new LDS data (all frags in regs)
    mma8(acc[1][0], a1f, b0f);
    BARR; SCHEDB;

    // ---- phase 3: quadrant (1,1) ----
    stA(2, bn, kn); stA(3, bn, kn);
    VMCNT4;          // boundary: covers t+1 p0's A0,A1,B0,B1
    BARR;
    mma8(acc[1][1], a1f, b1f);
    BARR; SCHEDB;
  }
  VMCNT0;            // drain trailing fake stages before exit

  // ---- epilogue: C/D layout col=lane&15, row=(lane>>4)*4+r  [m89-verified] ----
  const int orow = (lane >> 4) * 4;
  const int ocol = lane & 15;
  #pragma unroll
  for (int mq = 0; mq < 2; ++mq)
  #pragma unroll
  for (int nq = 0; nq < 2; ++nq)
  #pragma unroll
  for (int mi = 0; mi < 4; ++mi)
  #pragma unroll
  for (int ni = 0; ni < 2; ++ni) {
    const int rowb = m0 + mq*128 + wm*64 + mi*16 + orow;
    const int coln = n0 + nq*128 + wn*32 + ni*16 + ocol;
    #pragma unroll
    for (int r = 0; r < 4; ++r) {
      const int row = rowb + r;
      float v = acc[mq][nq][mi][ni][r];
      if (EPI == 0) {
        if (coln < 768) {
          const int seg = coln >> 8, cn = coln & 255;
          if (seg == 0)      v = 1.f / (1.f + __expf(-(v + b0[cn])));
          else if (seg == 1) v = v + b1[cn];
          else               v = tanhf(v + b2[cn]);
          outA[(size_t)row*768 + coln] = v;
        } else {
          const int col = coln - 768;
          outO[(size_t)row*1024 + col] = v + b3[col];
        }
      } else {
        outO[(size_t)row*1024 + coln] += v + b0[coln];
      }
    }
  }
}

// ---------------- scan: s_t = a*s + (1-a)*b ; cs = c*s ----------------
__global__ void scanA_kernel(const float* __restrict__ abc,
                             float* __restrict__ Asum, float* __restrict__ Usum) {
  int idx = blockIdx.x * blockDim.x + threadIdx.x;    // chunk*2048 + chain
  int chain = idx & (CHAINS - 1);
  int ch = idx >> 11;
  int bb = chain >> 8, n = chain & 255;
  const float* base = abc + (size_t)(bb*Tt + ch*TC) * 768;
  float A = 1.f, U = 0.f;
  for (int t = 0; t < TC; ++t) {
    float a = base[(size_t)t*768 + n];
    float b = base[(size_t)t*768 + 256 + n];
    U = a*U + (1.f - a)*b;
    A *= a;
  }
  Asum[idx] = A; Usum[idx] = U;
}

__global__ void scanB_kernel(const float* __restrict__ Asum, const float* __restrict__ Usum,
                             float* __restrict__ Spre) {
  int chain = blockIdx.x * blockDim.x + threadIdx.x;  // 0..2047
  float s = 0.f;
  for (int ch = 0; ch < NCH; ++ch) {
    int i = (ch << 11) + chain;
    Spre[i] = s;
    s = Asum[i]*s + Usum[i];
  }
}

__global__ void scanC_kernel(const float* __restrict__ abc, const float* __restrict__ Spre,
                             u16* __restrict__ cs) {
  int idx = blockIdx.x * blockDim.x + threadIdx.x;
  int chain = idx & (CHAINS - 1);
  int ch = idx >> 11;
  int bb = chain >> 8, n = chain & 255;
  const float* base = abc + (size_t)(bb*Tt + ch*TC) * 768;
  u16* csb = cs + (size_t)(bb*Tt + ch*TC) * 256 + n;
  float s = Spre[idx];
  for (int t = 0; t < TC; ++t) {
    float a = base[(size_t)t*768 + n];
    float b = base[(size_t)t*768 + 256 + n];
    float c = base[(size_t)t*768 + 512 + n];
    s = a*s + (1.f - a)*b;
    csb[(size_t)t*256] = f2bf(c*s);
  }
}

extern "C" void kernel_launch(void* const* d_in, const int* in_sizes, int n_in,
                              void* d_out, int out_size, void* d_ws, size_t ws_size,
                              hipStream_t stream) {
  const float* x  = (const float*)d_in[0];
  const float* Wa = (const float*)d_in[1];
  const float* ba = (const float*)d_in[2];
  const float* Wb = (const float*)d_in[3];
  const float* bb = (const float*)d_in[4];
  const float* Wc = (const float*)d_in[5];
  const float* bc = (const float*)d_in[6];
  const float* Wd = (const float*)d_in[7];
  const float* bd = (const float*)d_in[8];
  const float* Wy = (const float*)d_in[9];
  const float* by = (const float*)d_in[10];
  float* out = (float*)d_out;
  char* ws = (char*)d_ws;

  // workspace layout (bytes)
  u16*  xb    = (u16*) (ws + 0);          // 16384*1024*2 = 33,554,432
  u16*  Wcomb = (u16*) (ws + 33554432);   // 1792*1024*2  =  3,670,016
  u16*  Wyt   = (u16*) (ws + 37224448);   // 1024*256*2   =    524,288
  float* abc  = (float*)(ws + 37748736);  // 16384*768*4  = 50,331,648
  u16*  cs    = (u16*) (ws + 88080384);   // 16384*256*2  =  8,388,608
  float* Asum = (float*)(ws + 96468992);  // 2048*32*4    =    262,144
  float* Usum = (float*)(ws + 96731136);  //                  262,144
  float* Spre = (float*)(ws + 96993280);  //                  262,144

  // 1) convert x to bf16
  cvt_x_kernel<<<Mm*Dd/4/256, 256, 0, stream>>>(x, xb);
  // 2) pack weights (transposed bf16, [Wa|Wb|Wc|Wd] fused)
  pack_w_kernel<<<dim3(32, 32, 5), 256, 0, stream>>>(Wa, Wb, Wc, Wd, Wy, Wcomb, Wyt);
  // 3) fused 8-phase GEMM: abc = act(x@[Wa|Wb|Wc]+bias), out = x@Wd + bd
  //    grid = (16384/256) * (1792/256) = 64*7 = 448 (divisible by 8)
  gemm8p_kernel<0><<<448, 512, 131072, stream>>>(
      xb, Wcomb, Dd, NCOMB/256, abc, out, ba, bb, bc, bd);
  // 4) chunked scan
  scanA_kernel<<<CHAINS*NCH/256, 256, 0, stream>>>(abc, Asum, Usum);
  scanB_kernel<<<CHAINS/256, 256, 0, stream>>>(Asum, Usum, Spre);
  scanC_kernel<<<CHAINS*NCH/256, 256, 0, stream>>>(abc, Spre, cs);
  // 5) out += cs @ Wy + by  (grid = 64*4 = 256, divisible by 8)
  gemm8p_kernel<2><<<256, 512, 131072, stream>>>(
      cs, Wyt, Nn, Dd/256, nullptr, out, by, nullptr, nullptr, nullptr);
}